// Round 2
// baseline (154.440 us; speedup 1.0000x reference)
//
#include <hip/hip_runtime.h>

constexpr int Bn = 1024;
constexpr int Nn = 128;   // pred points per batch
constexpr int Mn = 128;   // gt points per batch

// Partials + completion ticket in module globals (d_ws unused; R1 established
// the harness poison-fills the workspace regardless of use).
// Self-consistent across graph replays: last block resets g_count to 0.
__device__ float4       g_part[Bn];
__device__ unsigned int g_count = 0;

// Phase A insight (unchanged): interp[m,t] = a + (t/10)*(b-a); dist quadratic
// in t -> evaluate only the clamped discrete vertex. Per-segment constants
// precomputed once per block.
//
// Merged scan (R1): wave w owns index range [32w,32w+32) of BOTH segments
// (phase A) and pred anchors (phase B); each lane holds 2 points in registers,
// so each wave-uniform broadcast LDS read serves 6 point-evaluations.
//
// R2: dm_final folded in via last-block ticket (removes one serialized launch
// -- the 1-block finalize kernel was pure launch/drain latency).

__global__ __launch_bounds__(256) void dm_main(
    const float2* __restrict__ ini,    // [B,N]
    const float2* __restrict__ pred,   // [B,N]
    const float2* __restrict__ gt,     // [B,M]
    const float*  __restrict__ kpm,    // [B,M]
    float* __restrict__ out)           // [1]
{
    __shared__ float4 s_segA[Mn];      // a.x, a.y, e.x, e.y
    __shared__ float2 s_segB[Mn];      // ee, -10*rcp(ee)
    __shared__ float2 s_ini[Nn];
    __shared__ float2 s_pred[Nn];
    __shared__ float2 s_gt[Mn];
    __shared__ float4 s_cA[4][Nn];     // per-wave phase-A candidates: d, s, m
    __shared__ float2 s_cB[4][Mn];     // per-wave phase-B candidates: d, j
    __shared__ float  s_red[3][4];
    __shared__ bool   s_last;

    const int b   = blockIdx.x;
    const int tid = threadIdx.x;

    // kpm for the gt point this thread owns in the combine step (tid>=128);
    // issued at kernel start so latency hides under the scan.
    float kw = 0.f;
    if (tid >= Nn) kw = kpm[b*Mn + (tid - Nn)];

    // ---- stage, split across the two thread halves ----
    if (tid < Mn) {
        const float2 cur = gt[b*Mn + tid];
        const float2 prv = gt[b*Mn + ((tid + Mn - 1) & (Mn - 1))];
        const float ex = cur.x - prv.x, ey = cur.y - prv.y;
        const float ee = fmaxf(fmaf(ex, ex, ey*ey), 1e-30f);  // degenerate-seg guard
        const float nr = -10.0f * __builtin_amdgcn_rcpf(ee);
        s_segA[tid] = make_float4(prv.x, prv.y, ex, ey);
        s_segB[tid] = make_float2(ee, nr);
        s_gt[tid]   = cur;
    } else {
        const int t = tid - Mn;
        s_ini[t]  = ini[b*Nn + t];
        s_pred[t] = pred[b*Nn + t];
    }
    __syncthreads();

    const int lane  = tid & 63;
    const int w     = tid >> 6;
    const int mbase = w * 32;          // this wave's segment/anchor range

    // two points per lane, held in registers
    const float2 p0 = s_ini[lane];
    const float2 p1 = s_ini[lane + 64];
    const float2 g0 = s_gt[lane];
    const float2 g1 = s_gt[lane + 64];

    float bd0 = 3.4e38f, bd1 = 3.4e38f;   // phase A best dist
    int   bm0 = 0,       bm1 = 0;          // best segment
    float bs0 = 0.f,     bs1 = 0.f;        // best s = t/10
    float cd0 = 3.4e38f, cd1 = 3.4e38f;   // phase B best dist
    int   cj0 = 0,       cj1 = 0;          // best anchor

    #pragma unroll 4
    for (int i = 0; i < 32; ++i) {
        const int m = mbase + i;                 // ascending -> first-min tie-break
        const float4 A  = s_segA[m];             // wave-uniform: broadcast read
        const float2 Bv = s_segB[m];
        const float2 q  = s_ini[m];              // phase-B anchor, broadcast read
        // ---- phase A, point 0 ----
        {
            const float fx = A.x - p0.x, fy = A.y - p0.y;
            const float fe = fmaf(fx, A.z, fy*A.w);
            const float ff = fmaf(fx, fx, fy*fy);
            float tv = fe * Bv.y;                       // vertex t = -10*fe/ee
            tv = fminf(fmaxf(rintf(tv), 0.f), 9.f);
            const float sp = tv * 0.1f;
            const float d  = fmaf(sp, fmaf(sp, Bv.x, fe + fe), ff);
            if (d < bd0) { bd0 = d; bm0 = m; bs0 = sp; }
        }
        // ---- phase A, point 1 ----
        {
            const float fx = A.x - p1.x, fy = A.y - p1.y;
            const float fe = fmaf(fx, A.z, fy*A.w);
            const float ff = fmaf(fx, fx, fy*fy);
            float tv = fe * Bv.y;
            tv = fminf(fmaxf(rintf(tv), 0.f), 9.f);
            const float sp = tv * 0.1f;
            const float d  = fmaf(sp, fmaf(sp, Bv.x, fe + fe), ff);
            if (d < bd1) { bd1 = d; bm1 = m; bs1 = sp; }
        }
        // ---- phase B, gt point 0 ----
        {
            const float dx = q.x - g0.x, dy = q.y - g0.y;
            const float d = fmaf(dx, dx, dy*dy);
            if (d < cd0) { cd0 = d; cj0 = m; }
        }
        // ---- phase B, gt point 1 ----
        {
            const float dx = q.x - g1.x, dy = q.y - g1.y;
            const float d = fmaf(dx, dx, dy*dy);
            if (d < cd1) { cd1 = d; cj1 = m; }
        }
    }

    // ---- publish per-wave candidates ----
    s_cA[w][lane]      = make_float4(bd0, bs0, __int_as_float(bm0), 0.f);
    s_cA[w][lane + 64] = make_float4(bd1, bs1, __int_as_float(bm1), 0.f);
    s_cB[w][lane]      = make_float2(cd0, __int_as_float(cj0));
    s_cB[w][lane + 64] = make_float2(cd1, __int_as_float(cj1));
    __syncthreads();

    // ---- cross-wave combine: waves cover ascending index ranges, so strict <
    //      in ascending wave order == lexicographic (d, index) first-min ----
    float sum_p2g = 0.f, sum_g2p = 0.f, sum_m = 0.f;
    if (tid < Nn) {
        const int n = tid;
        float best = 3.4e38f; float bs = 0.f; int bm = 0;
        #pragma unroll
        for (int w2 = 0; w2 < 4; ++w2) {
            const float4 c = s_cA[w2][n];
            if (c.x < best) { best = c.x; bs = c.y; bm = __float_as_int(c.z); }
        }
        const float4 A = s_segA[bm];
        const float ngx = fmaf(bs, A.z, A.x);
        const float ngy = fmaf(bs, A.w, A.y);
        const float2 pr = s_pred[n];
        sum_p2g = fabsf(pr.x - ngx) + fabsf(pr.y - ngy);
    } else {
        const int m = tid - Nn;
        float best = 3.4e38f; int nj = 0;
        #pragma unroll
        for (int w2 = 0; w2 < 4; ++w2) {
            const float2 c = s_cB[w2][m];
            if (c.x < best) { best = c.x; nj = __float_as_int(c.y); }
        }
        const float2 np_ = s_pred[nj];
        const float2 g   = s_gt[m];
        sum_g2p = kw * (fabsf(np_.x - g.x) + fabsf(np_.y - g.y));
        sum_m   = 2.0f * kw;
    }

    // ---- block reduction: 3 scalars over 256 threads ----
    #pragma unroll
    for (int off = 32; off > 0; off >>= 1) {
        sum_p2g += __shfl_down(sum_p2g, off);
        sum_g2p += __shfl_down(sum_g2p, off);
        sum_m   += __shfl_down(sum_m,   off);
    }
    const int wv = tid >> 6;
    if ((tid & 63) == 0) { s_red[0][wv] = sum_p2g; s_red[1][wv] = sum_g2p; s_red[2][wv] = sum_m; }
    __syncthreads();
    if (tid == 0) {
        g_part[b] = make_float4(s_red[0][0] + s_red[0][1] + s_red[0][2] + s_red[0][3],
                                s_red[1][0] + s_red[1][1] + s_red[1][2] + s_red[1][3],
                                s_red[2][0] + s_red[2][1] + s_red[2][2] + s_red[2][3], 0.f);
    }

    // ---- last-block finalize (replaces the dm_final launch) ----
    __threadfence();   // release g_part[b] to agent scope
    if (tid == 0) {
        const unsigned t = __hip_atomic_fetch_add(&g_count, 1u,
                                                  __ATOMIC_ACQ_REL,
                                                  __HIP_MEMORY_SCOPE_AGENT);
        s_last = (t == (unsigned)(Bn - 1));
    }
    __syncthreads();
    if (!s_last) return;

    __threadfence();   // acquire: all 1024 g_part entries now visible
    float A = 0.f, C = 0.f, M = 0.f;
    #pragma unroll
    for (int k = 0; k < 4; ++k) {
        const float4 v = g_part[tid + 256*k];
        A += v.x; C += v.y; M += v.z;
    }
    #pragma unroll
    for (int off = 32; off > 0; off >>= 1) {
        A += __shfl_down(A, off); C += __shfl_down(C, off); M += __shfl_down(M, off);
    }
    __syncthreads();   // s_red reuse barrier (uniform: all 256 threads here)
    if ((tid & 63) == 0) { s_red[0][wv] = A; s_red[1][wv] = C; s_red[2][wv] = M; }
    __syncthreads();
    if (tid == 0) {
        const float At = s_red[0][0] + s_red[0][1] + s_red[0][2] + s_red[0][3];
        const float Ct = s_red[1][0] + s_red[1][1] + s_red[1][2] + s_red[1][3];
        const float Mt = s_red[2][0] + s_red[2][1] + s_red[2][2] + s_red[2][3];
        // loss = ( masked_gt2pred/(mask_sum+1) + pred2gt_sum/(B*N*2) ) / 2
        out[0] = (Ct / (Mt + 1.0f) + At * (1.0f / 262144.0f)) * 0.5f;
        g_count = 0;   // self-reset for the next graph replay
    }
}

extern "C" void kernel_launch(void* const* d_in, const int* in_sizes, int n_in,
                              void* d_out, int out_size, void* d_ws, size_t ws_size,
                              hipStream_t stream)
{
    const float2* ini  = (const float2*)d_in[0];
    const float2* pred = (const float2*)d_in[1];
    const float2* gt   = (const float2*)d_in[2];
    const float*  kpm  = (const float*)d_in[3];
    float* out = (float*)d_out;
    // d_ws intentionally unused; single fused launch.

    dm_main<<<Bn, 256, 0, stream>>>(ini, pred, gt, kpm, out);
}

// Round 3
// 78.488 us; speedup vs baseline: 1.9677x; 1.9677x over previous
//
#include <hip/hip_runtime.h>

constexpr int Bn = 1024;
constexpr int Nn = 128;   // pred points per batch
constexpr int Mn = 128;   // gt points per batch

// Partials + completion ticket in module globals (d_ws unused; R1 established
// the harness poison-fills the workspace regardless of use).
// Self-consistent across graph replays: last block resets g_count to 0, and
// stream serialization orders that reset before the next replay's RMWs.
__device__ float4       g_part[Bn];
__device__ unsigned int g_count = 0;

// Phase A insight (unchanged): interp[m,t] = a + (t/10)*(b-a); dist quadratic
// in t -> evaluate only the clamped discrete vertex. Per-segment constants
// precomputed once per block.
//
// Merged scan (R1): wave w owns index range [32w,32w+32) of BOTH segments
// (phase A) and pred anchors (phase B); each lane holds 2 points in registers,
// so each wave-uniform broadcast LDS read serves 6 point-evaluations.
//
// R3: last-block ticket with MINIMAL coherence traffic. R2's 99us dm_main was
// fence storm: __threadfence() in the all-threads path (4096 waves x 2) plus
// per-block ACQ_REL RMW, each lowering to buffer_wbl2/buffer_inv on the
// non-coherent per-XCD L2s. Now: ONE release-RMW per block (tid0; its release
// already orders the preceding g_part[b] store -> no separate fence), and ONE
// acquire threadfence in the entire grid (last block's tid0; its buffer_inv
// covers the CU's L1 and the XCD's L2 before the block's normal g_part reads).

__global__ __launch_bounds__(256) void dm_main(
    const float2* __restrict__ ini,    // [B,N]
    const float2* __restrict__ pred,   // [B,N]
    const float2* __restrict__ gt,     // [B,M]
    const float*  __restrict__ kpm,    // [B,M]
    float* __restrict__ out)           // [1]
{
    __shared__ float4 s_segA[Mn];      // a.x, a.y, e.x, e.y
    __shared__ float2 s_segB[Mn];      // ee, -10*rcp(ee)
    __shared__ float2 s_ini[Nn];
    __shared__ float2 s_pred[Nn];
    __shared__ float2 s_gt[Mn];
    __shared__ float4 s_cA[4][Nn];     // per-wave phase-A candidates: d, s, m
    __shared__ float2 s_cB[4][Mn];     // per-wave phase-B candidates: d, j
    __shared__ float  s_red[3][4];
    __shared__ bool   s_last;

    const int b   = blockIdx.x;
    const int tid = threadIdx.x;

    // kpm for the gt point this thread owns in the combine step (tid>=128);
    // issued at kernel start so latency hides under the scan.
    float kw = 0.f;
    if (tid >= Nn) kw = kpm[b*Mn + (tid - Nn)];

    // ---- stage, split across the two thread halves ----
    if (tid < Mn) {
        const float2 cur = gt[b*Mn + tid];
        const float2 prv = gt[b*Mn + ((tid + Mn - 1) & (Mn - 1))];
        const float ex = cur.x - prv.x, ey = cur.y - prv.y;
        const float ee = fmaxf(fmaf(ex, ex, ey*ey), 1e-30f);  // degenerate-seg guard
        const float nr = -10.0f * __builtin_amdgcn_rcpf(ee);
        s_segA[tid] = make_float4(prv.x, prv.y, ex, ey);
        s_segB[tid] = make_float2(ee, nr);
        s_gt[tid]   = cur;
    } else {
        const int t = tid - Mn;
        s_ini[t]  = ini[b*Nn + t];
        s_pred[t] = pred[b*Nn + t];
    }
    __syncthreads();

    const int lane  = tid & 63;
    const int w     = tid >> 6;
    const int mbase = w * 32;          // this wave's segment/anchor range

    // two points per lane, held in registers
    const float2 p0 = s_ini[lane];
    const float2 p1 = s_ini[lane + 64];
    const float2 g0 = s_gt[lane];
    const float2 g1 = s_gt[lane + 64];

    float bd0 = 3.4e38f, bd1 = 3.4e38f;   // phase A best dist
    int   bm0 = 0,       bm1 = 0;          // best segment
    float bs0 = 0.f,     bs1 = 0.f;        // best s = t/10
    float cd0 = 3.4e38f, cd1 = 3.4e38f;   // phase B best dist
    int   cj0 = 0,       cj1 = 0;          // best anchor

    #pragma unroll 4
    for (int i = 0; i < 32; ++i) {
        const int m = mbase + i;                 // ascending -> first-min tie-break
        const float4 A  = s_segA[m];             // wave-uniform: broadcast read
        const float2 Bv = s_segB[m];
        const float2 q  = s_ini[m];              // phase-B anchor, broadcast read
        // ---- phase A, point 0 ----
        {
            const float fx = A.x - p0.x, fy = A.y - p0.y;
            const float fe = fmaf(fx, A.z, fy*A.w);
            const float ff = fmaf(fx, fx, fy*fy);
            float tv = fe * Bv.y;                       // vertex t = -10*fe/ee
            tv = fminf(fmaxf(rintf(tv), 0.f), 9.f);
            const float sp = tv * 0.1f;
            const float d  = fmaf(sp, fmaf(sp, Bv.x, fe + fe), ff);
            if (d < bd0) { bd0 = d; bm0 = m; bs0 = sp; }
        }
        // ---- phase A, point 1 ----
        {
            const float fx = A.x - p1.x, fy = A.y - p1.y;
            const float fe = fmaf(fx, A.z, fy*A.w);
            const float ff = fmaf(fx, fx, fy*fy);
            float tv = fe * Bv.y;
            tv = fminf(fmaxf(rintf(tv), 0.f), 9.f);
            const float sp = tv * 0.1f;
            const float d  = fmaf(sp, fmaf(sp, Bv.x, fe + fe), ff);
            if (d < bd1) { bd1 = d; bm1 = m; bs1 = sp; }
        }
        // ---- phase B, gt point 0 ----
        {
            const float dx = q.x - g0.x, dy = q.y - g0.y;
            const float d = fmaf(dx, dx, dy*dy);
            if (d < cd0) { cd0 = d; cj0 = m; }
        }
        // ---- phase B, gt point 1 ----
        {
            const float dx = q.x - g1.x, dy = q.y - g1.y;
            const float d = fmaf(dx, dx, dy*dy);
            if (d < cd1) { cd1 = d; cj1 = m; }
        }
    }

    // ---- publish per-wave candidates ----
    s_cA[w][lane]      = make_float4(bd0, bs0, __int_as_float(bm0), 0.f);
    s_cA[w][lane + 64] = make_float4(bd1, bs1, __int_as_float(bm1), 0.f);
    s_cB[w][lane]      = make_float2(cd0, __int_as_float(cj0));
    s_cB[w][lane + 64] = make_float2(cd1, __int_as_float(cj1));
    __syncthreads();

    // ---- cross-wave combine: waves cover ascending index ranges, so strict <
    //      in ascending wave order == lexicographic (d, index) first-min ----
    float sum_p2g = 0.f, sum_g2p = 0.f, sum_m = 0.f;
    if (tid < Nn) {
        const int n = tid;
        float best = 3.4e38f; float bs = 0.f; int bm = 0;
        #pragma unroll
        for (int w2 = 0; w2 < 4; ++w2) {
            const float4 c = s_cA[w2][n];
            if (c.x < best) { best = c.x; bs = c.y; bm = __float_as_int(c.z); }
        }
        const float4 A = s_segA[bm];
        const float ngx = fmaf(bs, A.z, A.x);
        const float ngy = fmaf(bs, A.w, A.y);
        const float2 pr = s_pred[n];
        sum_p2g = fabsf(pr.x - ngx) + fabsf(pr.y - ngy);
    } else {
        const int m = tid - Nn;
        float best = 3.4e38f; int nj = 0;
        #pragma unroll
        for (int w2 = 0; w2 < 4; ++w2) {
            const float2 c = s_cB[w2][m];
            if (c.x < best) { best = c.x; nj = __float_as_int(c.y); }
        }
        const float2 np_ = s_pred[nj];
        const float2 g   = s_gt[m];
        sum_g2p = kw * (fabsf(np_.x - g.x) + fabsf(np_.y - g.y));
        sum_m   = 2.0f * kw;
    }

    // ---- block reduction: 3 scalars over 256 threads ----
    #pragma unroll
    for (int off = 32; off > 0; off >>= 1) {
        sum_p2g += __shfl_down(sum_p2g, off);
        sum_g2p += __shfl_down(sum_g2p, off);
        sum_m   += __shfl_down(sum_m,   off);
    }
    const int wv = tid >> 6;
    if ((tid & 63) == 0) { s_red[0][wv] = sum_p2g; s_red[1][wv] = sum_g2p; s_red[2][wv] = sum_m; }
    __syncthreads();

    // ---- ticket: tid0 only; release-RMW orders the g_part[b] store ----
    if (tid == 0) {
        g_part[b] = make_float4(s_red[0][0] + s_red[0][1] + s_red[0][2] + s_red[0][3],
                                s_red[1][0] + s_red[1][1] + s_red[1][2] + s_red[1][3],
                                s_red[2][0] + s_red[2][1] + s_red[2][2] + s_red[2][3], 0.f);
        const unsigned t = __hip_atomic_fetch_add(&g_count, 1u,
                                                  __ATOMIC_RELEASE,
                                                  __HIP_MEMORY_SCOPE_AGENT);
        s_last = (t == (unsigned)(Bn - 1));
        if (s_last) __threadfence();   // the ONLY acquire fence in the grid:
                                       // invalidates this CU's L1 + XCD's L2
                                       // before the block's normal g_part reads
    }
    __syncthreads();
    if (!s_last) return;

    // ---- last-block finalize (replaces the dm_final launch) ----
    float A = 0.f, C = 0.f, M = 0.f;
    #pragma unroll
    for (int k = 0; k < 4; ++k) {
        const float4 v = g_part[tid + 256*k];
        A += v.x; C += v.y; M += v.z;
    }
    #pragma unroll
    for (int off = 32; off > 0; off >>= 1) {
        A += __shfl_down(A, off); C += __shfl_down(C, off); M += __shfl_down(M, off);
    }
    __syncthreads();   // s_red reuse barrier (uniform: all 256 threads here)
    if ((tid & 63) == 0) { s_red[0][wv] = A; s_red[1][wv] = C; s_red[2][wv] = M; }
    __syncthreads();
    if (tid == 0) {
        const float At = s_red[0][0] + s_red[0][1] + s_red[0][2] + s_red[0][3];
        const float Ct = s_red[1][0] + s_red[1][1] + s_red[1][2] + s_red[1][3];
        const float Mt = s_red[2][0] + s_red[2][1] + s_red[2][2] + s_red[2][3];
        // loss = ( masked_gt2pred/(mask_sum+1) + pred2gt_sum/(B*N*2) ) / 2
        out[0] = (Ct / (Mt + 1.0f) + At * (1.0f / 262144.0f)) * 0.5f;
        g_count = 0;   // self-reset; stream serialization orders this before
                       // the next replay's first RMW
    }
}

extern "C" void kernel_launch(void* const* d_in, const int* in_sizes, int n_in,
                              void* d_out, int out_size, void* d_ws, size_t ws_size,
                              hipStream_t stream)
{
    const float2* ini  = (const float2*)d_in[0];
    const float2* pred = (const float2*)d_in[1];
    const float2* gt   = (const float2*)d_in[2];
    const float*  kpm  = (const float*)d_in[3];
    float* out = (float*)d_out;
    // d_ws intentionally unused; single fused launch.

    dm_main<<<Bn, 256, 0, stream>>>(ini, pred, gt, kpm, out);
}

// Round 4
// 77.722 us; speedup vs baseline: 1.9871x; 1.0098x over previous
//
#include <hip/hip_runtime.h>

constexpr int Bn = 1024;
constexpr int Nn = 128;   // pred points per batch
constexpr int Mn = 128;   // gt points per batch

// R4 sync design: the ONLY data crossing XCDs is 12 B/block. Instead of
// release-fencing (R3: per-block buffer_wbl2 = full L2 writeback, ~12-15us
// aggregate), the 12 bytes are published with agent-scope RELAXED atomic
// stores (lower to sc1 write-through -> land at the coherent memory-side
// IF$), ordered before a RELAXED agent ticket RMW by a raw
// `s_waitcnt vmcnt(0)` (sc1 store ack == globally visible). The finalizer
// reads slots with relaxed agent (sc1) loads, bypassing its stale L1/L2.
// Zero wbl2 / zero inv / zero threadfence in the whole grid.
// Chain: each block's slots at IF$ before its RMW; RMW #1023 is last; the
// finalizer's sc1 loads hit IF$ directly.
__device__ unsigned long long g_ab[Bn];   // packed (float A, float C)
__device__ unsigned int       g_m[Bn];    // float M bits
__device__ unsigned int       g_count = 0; // self-reset by finalizer each replay

// Phase A insight (unchanged): interp[m,t] = a + (t/10)*(b-a); dist quadratic
// in t -> evaluate only the clamped discrete vertex. Per-segment constants
// precomputed once per block.
// Merged scan (R1): wave w owns index range [32w,32w+32) of BOTH segments
// (phase A) and pred anchors (phase B); each lane holds 2 points in registers.

__global__ __launch_bounds__(256) void dm_main(
    const float2* __restrict__ ini,    // [B,N]
    const float2* __restrict__ pred,   // [B,N]
    const float2* __restrict__ gt,     // [B,M]
    const float*  __restrict__ kpm,    // [B,M]
    float* __restrict__ out)           // [1]
{
    __shared__ float4 s_segA[Mn];      // a.x, a.y, e.x, e.y
    __shared__ float2 s_segB[Mn];      // ee, -10*rcp(ee)
    __shared__ float2 s_ini[Nn];
    __shared__ float2 s_pred[Nn];
    __shared__ float2 s_gt[Mn];
    __shared__ float4 s_cA[4][Nn];     // per-wave phase-A candidates: d, s, m
    __shared__ float2 s_cB[4][Mn];     // per-wave phase-B candidates: d, j
    __shared__ float  s_red[3][4];
    __shared__ bool   s_last;

    const int b   = blockIdx.x;
    const int tid = threadIdx.x;

    // kpm for the gt point this thread owns in the combine step (tid>=128);
    // issued at kernel start so latency hides under the scan.
    float kw = 0.f;
    if (tid >= Nn) kw = kpm[b*Mn + (tid - Nn)];

    // ---- stage, split across the two thread halves ----
    if (tid < Mn) {
        const float2 cur = gt[b*Mn + tid];
        const float2 prv = gt[b*Mn + ((tid + Mn - 1) & (Mn - 1))];
        const float ex = cur.x - prv.x, ey = cur.y - prv.y;
        const float ee = fmaxf(fmaf(ex, ex, ey*ey), 1e-30f);  // degenerate-seg guard
        const float nr = -10.0f * __builtin_amdgcn_rcpf(ee);
        s_segA[tid] = make_float4(prv.x, prv.y, ex, ey);
        s_segB[tid] = make_float2(ee, nr);
        s_gt[tid]   = cur;
    } else {
        const int t = tid - Mn;
        s_ini[t]  = ini[b*Nn + t];
        s_pred[t] = pred[b*Nn + t];
    }
    __syncthreads();

    const int lane  = tid & 63;
    const int w     = tid >> 6;
    const int mbase = w * 32;          // this wave's segment/anchor range

    // two points per lane, held in registers
    const float2 p0 = s_ini[lane];
    const float2 p1 = s_ini[lane + 64];
    const float2 g0 = s_gt[lane];
    const float2 g1 = s_gt[lane + 64];

    float bd0 = 3.4e38f, bd1 = 3.4e38f;   // phase A best dist
    int   bm0 = 0,       bm1 = 0;          // best segment
    float bs0 = 0.f,     bs1 = 0.f;        // best s = t/10
    float cd0 = 3.4e38f, cd1 = 3.4e38f;   // phase B best dist
    int   cj0 = 0,       cj1 = 0;          // best anchor

    #pragma unroll 4
    for (int i = 0; i < 32; ++i) {
        const int m = mbase + i;                 // ascending -> first-min tie-break
        const float4 A  = s_segA[m];             // wave-uniform: broadcast read
        const float2 Bv = s_segB[m];
        const float2 q  = s_ini[m];              // phase-B anchor, broadcast read
        // ---- phase A, point 0 ----
        {
            const float fx = A.x - p0.x, fy = A.y - p0.y;
            const float fe = fmaf(fx, A.z, fy*A.w);
            const float ff = fmaf(fx, fx, fy*fy);
            float tv = fe * Bv.y;                       // vertex t = -10*fe/ee
            tv = fminf(fmaxf(rintf(tv), 0.f), 9.f);
            const float sp = tv * 0.1f;
            const float d  = fmaf(sp, fmaf(sp, Bv.x, fe + fe), ff);
            if (d < bd0) { bd0 = d; bm0 = m; bs0 = sp; }
        }
        // ---- phase A, point 1 ----
        {
            const float fx = A.x - p1.x, fy = A.y - p1.y;
            const float fe = fmaf(fx, A.z, fy*A.w);
            const float ff = fmaf(fx, fx, fy*fy);
            float tv = fe * Bv.y;
            tv = fminf(fmaxf(rintf(tv), 0.f), 9.f);
            const float sp = tv * 0.1f;
            const float d  = fmaf(sp, fmaf(sp, Bv.x, fe + fe), ff);
            if (d < bd1) { bd1 = d; bm1 = m; bs1 = sp; }
        }
        // ---- phase B, gt point 0 ----
        {
            const float dx = q.x - g0.x, dy = q.y - g0.y;
            const float d = fmaf(dx, dx, dy*dy);
            if (d < cd0) { cd0 = d; cj0 = m; }
        }
        // ---- phase B, gt point 1 ----
        {
            const float dx = q.x - g1.x, dy = q.y - g1.y;
            const float d = fmaf(dx, dx, dy*dy);
            if (d < cd1) { cd1 = d; cj1 = m; }
        }
    }

    // ---- publish per-wave candidates ----
    s_cA[w][lane]      = make_float4(bd0, bs0, __int_as_float(bm0), 0.f);
    s_cA[w][lane + 64] = make_float4(bd1, bs1, __int_as_float(bm1), 0.f);
    s_cB[w][lane]      = make_float2(cd0, __int_as_float(cj0));
    s_cB[w][lane + 64] = make_float2(cd1, __int_as_float(cj1));
    __syncthreads();

    // ---- cross-wave combine: waves cover ascending index ranges, so strict <
    //      in ascending wave order == lexicographic (d, index) first-min ----
    float sum_p2g = 0.f, sum_g2p = 0.f, sum_m = 0.f;
    if (tid < Nn) {
        const int n = tid;
        float best = 3.4e38f; float bs = 0.f; int bm = 0;
        #pragma unroll
        for (int w2 = 0; w2 < 4; ++w2) {
            const float4 c = s_cA[w2][n];
            if (c.x < best) { best = c.x; bs = c.y; bm = __float_as_int(c.z); }
        }
        const float4 A = s_segA[bm];
        const float ngx = fmaf(bs, A.z, A.x);
        const float ngy = fmaf(bs, A.w, A.y);
        const float2 pr = s_pred[n];
        sum_p2g = fabsf(pr.x - ngx) + fabsf(pr.y - ngy);
    } else {
        const int m = tid - Nn;
        float best = 3.4e38f; int nj = 0;
        #pragma unroll
        for (int w2 = 0; w2 < 4; ++w2) {
            const float2 c = s_cB[w2][m];
            if (c.x < best) { best = c.x; nj = __float_as_int(c.y); }
        }
        const float2 np_ = s_pred[nj];
        const float2 g   = s_gt[m];
        sum_g2p = kw * (fabsf(np_.x - g.x) + fabsf(np_.y - g.y));
        sum_m   = 2.0f * kw;
    }

    // ---- block reduction: 3 scalars over 256 threads ----
    #pragma unroll
    for (int off = 32; off > 0; off >>= 1) {
        sum_p2g += __shfl_down(sum_p2g, off);
        sum_g2p += __shfl_down(sum_g2p, off);
        sum_m   += __shfl_down(sum_m,   off);
    }
    const int wv = tid >> 6;
    if ((tid & 63) == 0) { s_red[0][wv] = sum_p2g; s_red[1][wv] = sum_g2p; s_red[2][wv] = sum_m; }
    __syncthreads();

    // ---- ticket: tid0 only; sc1 slot stores + vmcnt(0) + relaxed RMW ----
    if (tid == 0) {
        const float At = s_red[0][0] + s_red[0][1] + s_red[0][2] + s_red[0][3];
        const float Ct = s_red[1][0] + s_red[1][1] + s_red[1][2] + s_red[1][3];
        const float Mt = s_red[2][0] + s_red[2][1] + s_red[2][2] + s_red[2][3];
        const unsigned long long ab =
            ((unsigned long long)__float_as_uint(Ct) << 32) | __float_as_uint(At);
        __hip_atomic_store(&g_ab[b], ab, __ATOMIC_RELAXED, __HIP_MEMORY_SCOPE_AGENT);
        __hip_atomic_store(&g_m[b], __float_as_uint(Mt),
                           __ATOMIC_RELAXED, __HIP_MEMORY_SCOPE_AGENT);
        // sc1 store ack == visible at the coherent IF$; order it before the RMW
        asm volatile("s_waitcnt vmcnt(0)" ::: "memory");
        const unsigned t = __hip_atomic_fetch_add(&g_count, 1u,
                                                  __ATOMIC_RELAXED,
                                                  __HIP_MEMORY_SCOPE_AGENT);
        s_last = (t == (unsigned)(Bn - 1));
    }
    __syncthreads();
    if (!s_last) return;

    // ---- last-block finalize (replaces the dm_final launch) ----
    float A = 0.f, C = 0.f, M = 0.f;
    #pragma unroll
    for (int k = 0; k < 4; ++k) {
        const int idx = tid + 256*k;
        const unsigned long long ab =
            __hip_atomic_load(&g_ab[idx], __ATOMIC_RELAXED, __HIP_MEMORY_SCOPE_AGENT);
        const unsigned mm =
            __hip_atomic_load(&g_m[idx], __ATOMIC_RELAXED, __HIP_MEMORY_SCOPE_AGENT);
        A += __uint_as_float((unsigned)(ab & 0xffffffffull));
        C += __uint_as_float((unsigned)(ab >> 32));
        M += __uint_as_float(mm);
    }
    #pragma unroll
    for (int off = 32; off > 0; off >>= 1) {
        A += __shfl_down(A, off); C += __shfl_down(C, off); M += __shfl_down(M, off);
    }
    __syncthreads();   // s_red reuse barrier (uniform: all 256 threads here)
    if ((tid & 63) == 0) { s_red[0][wv] = A; s_red[1][wv] = C; s_red[2][wv] = M; }
    __syncthreads();
    if (tid == 0) {
        const float At = s_red[0][0] + s_red[0][1] + s_red[0][2] + s_red[0][3];
        const float Ct = s_red[1][0] + s_red[1][1] + s_red[1][2] + s_red[1][3];
        const float Mt = s_red[2][0] + s_red[2][1] + s_red[2][2] + s_red[2][3];
        // loss = ( masked_gt2pred/(mask_sum+1) + pred2gt_sum/(B*N*2) ) / 2
        out[0] = (Ct / (Mt + 1.0f) + At * (1.0f / 262144.0f)) * 0.5f;
        // self-reset; kernel-end release + stream order publish it for the
        // next graph replay
        __hip_atomic_store(&g_count, 0u, __ATOMIC_RELAXED, __HIP_MEMORY_SCOPE_AGENT);
    }
}

extern "C" void kernel_launch(void* const* d_in, const int* in_sizes, int n_in,
                              void* d_out, int out_size, void* d_ws, size_t ws_size,
                              hipStream_t stream)
{
    const float2* ini  = (const float2*)d_in[0];
    const float2* pred = (const float2*)d_in[1];
    const float2* gt   = (const float2*)d_in[2];
    const float*  kpm  = (const float*)d_in[3];
    float* out = (float*)d_out;
    // d_ws intentionally unused; single fused launch.

    dm_main<<<Bn, 256, 0, stream>>>(ini, pred, gt, kpm, out);
}

// Round 5
// 72.499 us; speedup vs baseline: 2.1302x; 1.0721x over previous
//
#include <hip/hip_runtime.h>

constexpr int Bn = 1024;
constexpr int Nn = 128;   // pred points per batch
constexpr int Mn = 128;   // gt points per batch

// R5 sync: hierarchical completion ticket.
// R4 post-mortem: 1024 same-address agent RMWs serialize at one IF$ bank
// (~15 ns each = ~15 us aggregate -- the whole fused-kernel overhead).
// Now: 64 group counters (16 blocks each, strided 64 B -> different IF$
// banks, serialize in PARALLEL), plus one level-2 counter touched by only
// the 64 group-last blocks. Worst same-address chain ~64 RMWs ~ 1 us.
// Visibility chain (unchanged from R4): each block's 12 B of partials is
// published with agent-scope relaxed (sc1, write-through-to-IF$) stores,
// IF$-acked via `s_waitcnt vmcnt(0)` BEFORE its level-1 RMW; group-last
// ticket 15 => group's slots durable; level-2 ticket 63 => all 1024 slots
// durable; finalizer reads slots with sc1 loads (bypass stale L1/L2).
// Zero wbl2 / zero inv / zero threadfence anywhere.
__device__ unsigned long long g_ab[Bn];        // packed (float A, float C)
__device__ unsigned int       g_m[Bn];         // float M bits
__device__ unsigned int       g_c1[64 * 16];   // level-1 tickets, 64 B stride
__device__ unsigned int       g_c2 = 0;        // level-2 ticket
// All counters are zero-initialized at load; the finalizer re-zeros them
// each call (it runs strictly after every RMW of the replay -> no race).

// Phase A insight (unchanged): interp[m,t] = a + (t/10)*(b-a); dist quadratic
// in t -> evaluate only the clamped discrete vertex. Per-segment constants
// precomputed once per block.
// Merged scan (R1): wave w owns index range [32w,32w+32) of BOTH segments
// (phase A) and pred anchors (phase B); each lane holds 2 points in registers.

__global__ __launch_bounds__(256) void dm_main(
    const float2* __restrict__ ini,    // [B,N]
    const float2* __restrict__ pred,   // [B,N]
    const float2* __restrict__ gt,     // [B,M]
    const float*  __restrict__ kpm,    // [B,M]
    float* __restrict__ out)           // [1]
{
    __shared__ float4 s_segA[Mn];      // a.x, a.y, e.x, e.y
    __shared__ float2 s_segB[Mn];      // ee, -10*rcp(ee)
    __shared__ float2 s_ini[Nn];
    __shared__ float2 s_pred[Nn];
    __shared__ float2 s_gt[Mn];
    __shared__ float4 s_cA[4][Nn];     // per-wave phase-A candidates: d, s, m
    __shared__ float2 s_cB[4][Mn];     // per-wave phase-B candidates: d, j
    __shared__ float  s_red[3][4];
    __shared__ bool   s_last;

    const int b   = blockIdx.x;
    const int tid = threadIdx.x;

    // kpm for the gt point this thread owns in the combine step (tid>=128);
    // issued at kernel start so latency hides under the scan.
    float kw = 0.f;
    if (tid >= Nn) kw = kpm[b*Mn + (tid - Nn)];

    // ---- stage, split across the two thread halves ----
    if (tid < Mn) {
        const float2 cur = gt[b*Mn + tid];
        const float2 prv = gt[b*Mn + ((tid + Mn - 1) & (Mn - 1))];
        const float ex = cur.x - prv.x, ey = cur.y - prv.y;
        const float ee = fmaxf(fmaf(ex, ex, ey*ey), 1e-30f);  // degenerate-seg guard
        const float nr = -10.0f * __builtin_amdgcn_rcpf(ee);
        s_segA[tid] = make_float4(prv.x, prv.y, ex, ey);
        s_segB[tid] = make_float2(ee, nr);
        s_gt[tid]   = cur;
    } else {
        const int t = tid - Mn;
        s_ini[t]  = ini[b*Nn + t];
        s_pred[t] = pred[b*Nn + t];
    }
    __syncthreads();

    const int lane  = tid & 63;
    const int w     = tid >> 6;
    const int mbase = w * 32;          // this wave's segment/anchor range

    // two points per lane, held in registers
    const float2 p0 = s_ini[lane];
    const float2 p1 = s_ini[lane + 64];
    const float2 g0 = s_gt[lane];
    const float2 g1 = s_gt[lane + 64];

    float bd0 = 3.4e38f, bd1 = 3.4e38f;   // phase A best dist
    int   bm0 = 0,       bm1 = 0;          // best segment
    float bs0 = 0.f,     bs1 = 0.f;        // best s = t/10
    float cd0 = 3.4e38f, cd1 = 3.4e38f;   // phase B best dist
    int   cj0 = 0,       cj1 = 0;          // best anchor

    #pragma unroll 4
    for (int i = 0; i < 32; ++i) {
        const int m = mbase + i;                 // ascending -> first-min tie-break
        const float4 A  = s_segA[m];             // wave-uniform: broadcast read
        const float2 Bv = s_segB[m];
        const float2 q  = s_ini[m];              // phase-B anchor, broadcast read
        // ---- phase A, point 0 ----
        {
            const float fx = A.x - p0.x, fy = A.y - p0.y;
            const float fe = fmaf(fx, A.z, fy*A.w);
            const float ff = fmaf(fx, fx, fy*fy);
            float tv = fe * Bv.y;                       // vertex t = -10*fe/ee
            tv = fminf(fmaxf(rintf(tv), 0.f), 9.f);
            const float sp = tv * 0.1f;
            const float d  = fmaf(sp, fmaf(sp, Bv.x, fe + fe), ff);
            if (d < bd0) { bd0 = d; bm0 = m; bs0 = sp; }
        }
        // ---- phase A, point 1 ----
        {
            const float fx = A.x - p1.x, fy = A.y - p1.y;
            const float fe = fmaf(fx, A.z, fy*A.w);
            const float ff = fmaf(fx, fx, fy*fy);
            float tv = fe * Bv.y;
            tv = fminf(fmaxf(rintf(tv), 0.f), 9.f);
            const float sp = tv * 0.1f;
            const float d  = fmaf(sp, fmaf(sp, Bv.x, fe + fe), ff);
            if (d < bd1) { bd1 = d; bm1 = m; bs1 = sp; }
        }
        // ---- phase B, gt point 0 ----
        {
            const float dx = q.x - g0.x, dy = q.y - g0.y;
            const float d = fmaf(dx, dx, dy*dy);
            if (d < cd0) { cd0 = d; cj0 = m; }
        }
        // ---- phase B, gt point 1 ----
        {
            const float dx = q.x - g1.x, dy = q.y - g1.y;
            const float d = fmaf(dx, dx, dy*dy);
            if (d < cd1) { cd1 = d; cj1 = m; }
        }
    }

    // ---- publish per-wave candidates ----
    s_cA[w][lane]      = make_float4(bd0, bs0, __int_as_float(bm0), 0.f);
    s_cA[w][lane + 64] = make_float4(bd1, bs1, __int_as_float(bm1), 0.f);
    s_cB[w][lane]      = make_float2(cd0, __int_as_float(cj0));
    s_cB[w][lane + 64] = make_float2(cd1, __int_as_float(cj1));
    __syncthreads();

    // ---- cross-wave combine: waves cover ascending index ranges, so strict <
    //      in ascending wave order == lexicographic (d, index) first-min ----
    float sum_p2g = 0.f, sum_g2p = 0.f, sum_m = 0.f;
    if (tid < Nn) {
        const int n = tid;
        float best = 3.4e38f; float bs = 0.f; int bm = 0;
        #pragma unroll
        for (int w2 = 0; w2 < 4; ++w2) {
            const float4 c = s_cA[w2][n];
            if (c.x < best) { best = c.x; bs = c.y; bm = __float_as_int(c.z); }
        }
        const float4 A = s_segA[bm];
        const float ngx = fmaf(bs, A.z, A.x);
        const float ngy = fmaf(bs, A.w, A.y);
        const float2 pr = s_pred[n];
        sum_p2g = fabsf(pr.x - ngx) + fabsf(pr.y - ngy);
    } else {
        const int m = tid - Nn;
        float best = 3.4e38f; int nj = 0;
        #pragma unroll
        for (int w2 = 0; w2 < 4; ++w2) {
            const float2 c = s_cB[w2][m];
            if (c.x < best) { best = c.x; nj = __float_as_int(c.y); }
        }
        const float2 np_ = s_pred[nj];
        const float2 g   = s_gt[m];
        sum_g2p = kw * (fabsf(np_.x - g.x) + fabsf(np_.y - g.y));
        sum_m   = 2.0f * kw;
    }

    // ---- block reduction: 3 scalars over 256 threads ----
    #pragma unroll
    for (int off = 32; off > 0; off >>= 1) {
        sum_p2g += __shfl_down(sum_p2g, off);
        sum_g2p += __shfl_down(sum_g2p, off);
        sum_m   += __shfl_down(sum_m,   off);
    }
    const int wv = tid >> 6;
    if ((tid & 63) == 0) { s_red[0][wv] = sum_p2g; s_red[1][wv] = sum_g2p; s_red[2][wv] = sum_m; }
    __syncthreads();

    // ---- ticket (tid0): sc1 publish -> vmcnt(0) -> hierarchical RMWs ----
    if (tid == 0) {
        const float At = s_red[0][0] + s_red[0][1] + s_red[0][2] + s_red[0][3];
        const float Ct = s_red[1][0] + s_red[1][1] + s_red[1][2] + s_red[1][3];
        const float Mt = s_red[2][0] + s_red[2][1] + s_red[2][2] + s_red[2][3];
        const unsigned long long ab =
            ((unsigned long long)__float_as_uint(Ct) << 32) | __float_as_uint(At);
        __hip_atomic_store(&g_ab[b], ab, __ATOMIC_RELAXED, __HIP_MEMORY_SCOPE_AGENT);
        __hip_atomic_store(&g_m[b], __float_as_uint(Mt),
                           __ATOMIC_RELAXED, __HIP_MEMORY_SCOPE_AGENT);
        // sc1 store ack == durable at the coherent IF$; order before ticket
        asm volatile("s_waitcnt vmcnt(0)" ::: "memory");
        bool last = false;
        const unsigned t1 = __hip_atomic_fetch_add(&g_c1[(b >> 4) << 4], 1u,
                                                   __ATOMIC_RELAXED,
                                                   __HIP_MEMORY_SCOPE_AGENT);
        if (t1 == 15u) {   // group-last: my group's 16 blocks all published
            const unsigned t2 = __hip_atomic_fetch_add(&g_c2, 1u,
                                                       __ATOMIC_RELAXED,
                                                       __HIP_MEMORY_SCOPE_AGENT);
            last = (t2 == 63u);   // all 64 groups complete
        }
        s_last = last;
    }
    __syncthreads();
    if (!s_last) return;

    // ---- last-block finalize (replaces the dm_final launch) ----
    // reset tickets for the next graph replay (all RMWs of this replay are
    // already done -- we hold ticket 63); runs in parallel with slot loads
    if (tid < 64) {
        __hip_atomic_store(&g_c1[tid << 4], 0u, __ATOMIC_RELAXED,
                           __HIP_MEMORY_SCOPE_AGENT);
    } else if (tid == 64) {
        __hip_atomic_store(&g_c2, 0u, __ATOMIC_RELAXED,
                           __HIP_MEMORY_SCOPE_AGENT);
    }
    float A = 0.f, C = 0.f, M = 0.f;
    #pragma unroll
    for (int k = 0; k < 4; ++k) {
        const int idx = tid + 256*k;
        const unsigned long long ab =
            __hip_atomic_load(&g_ab[idx], __ATOMIC_RELAXED, __HIP_MEMORY_SCOPE_AGENT);
        const unsigned mm =
            __hip_atomic_load(&g_m[idx], __ATOMIC_RELAXED, __HIP_MEMORY_SCOPE_AGENT);
        A += __uint_as_float((unsigned)(ab & 0xffffffffull));
        C += __uint_as_float((unsigned)(ab >> 32));
        M += __uint_as_float(mm);
    }
    #pragma unroll
    for (int off = 32; off > 0; off >>= 1) {
        A += __shfl_down(A, off); C += __shfl_down(C, off); M += __shfl_down(M, off);
    }
    __syncthreads();   // s_red reuse barrier (uniform: all 256 threads here)
    if ((tid & 63) == 0) { s_red[0][wv] = A; s_red[1][wv] = C; s_red[2][wv] = M; }
    __syncthreads();
    if (tid == 0) {
        const float At = s_red[0][0] + s_red[0][1] + s_red[0][2] + s_red[0][3];
        const float Ct = s_red[1][0] + s_red[1][1] + s_red[1][2] + s_red[1][3];
        const float Mt = s_red[2][0] + s_red[2][1] + s_red[2][2] + s_red[2][3];
        // loss = ( masked_gt2pred/(mask_sum+1) + pred2gt_sum/(B*N*2) ) / 2
        out[0] = (Ct / (Mt + 1.0f) + At * (1.0f / 262144.0f)) * 0.5f;
    }
}

extern "C" void kernel_launch(void* const* d_in, const int* in_sizes, int n_in,
                              void* d_out, int out_size, void* d_ws, size_t ws_size,
                              hipStream_t stream)
{
    const float2* ini  = (const float2*)d_in[0];
    const float2* pred = (const float2*)d_in[1];
    const float2* gt   = (const float2*)d_in[2];
    const float*  kpm  = (const float*)d_in[3];
    float* out = (float*)d_out;
    // d_ws intentionally unused; single fused launch.

    dm_main<<<Bn, 256, 0, stream>>>(ini, pred, gt, kpm, out);
}